// Round 1
// baseline (1418.686 us; speedup 1.0000x reference)
//
#include <hip/hip_runtime.h>
#include <math.h>

// Problem dims
#define I_N 16
#define T_N 64
#define Q_N 196
#define K_N 32
#define E_N 512
#define H_N 8
#define D_N 64

// finfo(f32).min / sqrt(512) -- masked entries AFTER the /sqrt(E) scaling.
// Finite and identical for all masked entries => column softmax of a fully
// masked (t,k) column gives exactly uniform 1/196 (matches jax reference).
#define NEG_MASKED (-1.5038454e37f)
#define INV_SQRT_E (0.044194173824159216f)  // 1/sqrt(512)

// ---------------------------------------------------------------------------
// Mask dtype detection: bool may arrive as int32 {0,1}, float {0.f,1.f}, or
// packed bytes. Scan first 512 words (2048 B -- valid in every candidate).
// mode 0 = int32, 1 = float32, 2 = bytes
__global__ __launch_bounds__(512) void detect_mask_kernel(const unsigned int* __restrict__ mask,
                                                          int* __restrict__ flag) {
    __shared__ int notSimple, sawFloat;
    int tid = threadIdx.x;
    if (tid == 0) { notSimple = 0; sawFloat = 0; }
    __syncthreads();
    unsigned int v = mask[tid];
    if (v != 0u && v != 1u && v != 0x3f800000u) atomicOr(&notSimple, 1);
    if (v == 0x3f800000u) atomicOr(&sawFloat, 1);
    __syncthreads();
    if (tid == 0) flag[0] = notSimple ? 2 : (sawFloat ? 1 : 0);
}

// ---------------------------------------------------------------------------
// query projection: out[r, n] = sum_d x[r, d] * W[n, d],  r = (i*Q+q)*H + h
// One wave per row, 4 rows per block. W staged transposed+padded in LDS.
__global__ __launch_bounds__(256) void proj_q_kernel(const float* __restrict__ x,
                                                     const float* __restrict__ W,
                                                     float* __restrict__ out) {
    __shared__ float sWt[64 * 65];
    __shared__ float sX[256];
    int tid = threadIdx.x;
    for (int j = tid; j < 4096; j += 256) {
        int n = j >> 6, d = j & 63;
        sWt[d * 65 + n] = W[j];
    }
    int rowBase = blockIdx.x * 4;
    sX[tid] = x[rowBase * 64 + tid];
    __syncthreads();
    int wave = tid >> 6, lane = tid & 63;
    float acc = 0.f;
#pragma unroll
    for (int d = 0; d < 64; ++d) acc += sX[wave * 64 + d] * sWt[d * 65 + lane];
    out[(rowBase + wave) * 64 + lane] = acc;
}

// key + value projection in one pass over text rows.
__global__ __launch_bounds__(256) void proj_kv_kernel(const float* __restrict__ x,
                                                      const float* __restrict__ Wk,
                                                      const float* __restrict__ Wv,
                                                      float* __restrict__ kout,
                                                      float* __restrict__ vout) {
    __shared__ float sWkT[64 * 65];
    __shared__ float sWvT[64 * 65];
    __shared__ float sX[256];
    int tid = threadIdx.x;
    for (int j = tid; j < 4096; j += 256) {
        int n = j >> 6, d = j & 63;
        sWkT[d * 65 + n] = Wk[j];
        sWvT[d * 65 + n] = Wv[j];
    }
    int rowBase = blockIdx.x * 4;
    sX[tid] = x[rowBase * 64 + tid];
    __syncthreads();
    int wave = tid >> 6, lane = tid & 63;
    float ak = 0.f, av = 0.f;
#pragma unroll
    for (int d = 0; d < 64; ++d) {
        float xv = sX[wave * 64 + d];
        ak += xv * sWkT[d * 65 + lane];
        av += xv * sWvT[d * 65 + lane];
    }
    kout[(rowBase + wave) * 64 + lane] = ak;
    vout[(rowBase + wave) * 64 + lane] = av;
}

// ---------------------------------------------------------------------------
// Main attention kernel. One block per (i, t, h). 256 threads; thread = q row.
//  - S[q,k] = q.k scaled+masked -> staged in LDS (stride 33, conflict-free)
//  - row softmax (attention) from registers -> global
//  - col softmax (text_attention) in LDS, 8 threads/column -> coalesced write
//  - PV accumulate o[64] in registers, butterfly-reduce over q, write pooled SUM
__global__ __launch_bounds__(256) void attn_kernel(const float* __restrict__ qproj,
                                                   const float* __restrict__ kproj,
                                                   const float* __restrict__ vproj,
                                                   const int* __restrict__ mask,
                                                   const int* __restrict__ modeFlag,
                                                   float* __restrict__ attn_out,
                                                   float* __restrict__ tattn_out,
                                                   float* __restrict__ pooled) {
    __shared__ float sK[K_N * 64];
    __shared__ float sV[K_N * 64];
    __shared__ float sS[Q_N * 33];
    __shared__ float sPool[64];
    __shared__ float sMask[K_N];

    int tid = threadIdx.x;
    int bid = blockIdx.x;
    int h = bid & 7;
    int t = (bid >> 3) & 63;
    int i = bid >> 9;

    for (int j = tid; j < K_N * 64; j += 256) {
        int k = j >> 6, d = j & 63;
        int src = ((t * K_N + k) * H_N + h) * 64 + d;
        sK[j] = kproj[src];
        sV[j] = vproj[src];
    }
    int mode = modeFlag[0];
    if (tid < K_N) {
        int idx = t * K_N + tid;
        bool keep;
        if (mode == 2)      keep = ((const unsigned char*)mask)[idx] != 0;
        else if (mode == 1) keep = ((const float*)mask)[idx] != 0.0f;
        else                keep = mask[idx] != 0;
        sMask[tid] = keep ? 1.0f : 0.0f;
    }
    if (tid < 64) sPool[tid] = 0.f;
    __syncthreads();

    const float4* sKf4 = (const float4*)sK;
    const float4* sVf4 = (const float4*)sV;

    int q = tid;
    bool active = (q < Q_N);
    float s[K_N];

    if (active) {
#pragma unroll
        for (int k = 0; k < K_N; ++k) s[k] = 0.f;
        const float4* qrow = (const float4*)(qproj + ((i * Q_N + q) * H_N + h) * 64);
#pragma unroll
        for (int d4 = 0; d4 < 16; ++d4) {
            float4 qv = qrow[d4];
#pragma unroll
            for (int k = 0; k < K_N; ++k) {
                float4 kv = sKf4[k * 16 + d4];
                s[k] += qv.x * kv.x + qv.y * kv.y + qv.z * kv.z + qv.w * kv.w;
            }
        }
        float m = -INFINITY;
#pragma unroll
        for (int k = 0; k < K_N; ++k) {
            float v = (sMask[k] != 0.f) ? s[k] * INV_SQRT_E : NEG_MASKED;
            s[k] = v;
            sS[q * 33 + k] = v;
            m = fmaxf(m, v);
        }
        float sum = 0.f;
#pragma unroll
        for (int k = 0; k < K_N; ++k) {
            float e = __expf(s[k] - m);  // masked: exp(-1.5e37) -> 0
            s[k] = e;
            sum += e;
        }
        float r = 1.0f / sum;
#pragma unroll
        for (int k = 0; k < K_N; ++k) s[k] *= r;
        // attention row write: 32 consecutive floats
        float4* arow = (float4*)(attn_out + (size_t)bid * (Q_N * K_N) + q * K_N);
#pragma unroll
        for (int k4 = 0; k4 < 8; ++k4) {
            float4 v;
            v.x = s[k4 * 4 + 0]; v.y = s[k4 * 4 + 1];
            v.z = s[k4 * 4 + 2]; v.w = s[k4 * 4 + 3];
            arow[k4] = v;
        }
    }
    __syncthreads();

    // column softmax over q (8 threads per column, shuffle-reduce subs)
    {
        int k = tid >> 3, sub = tid & 7;
        float m = -INFINITY;
        for (int qq = sub; qq < Q_N; qq += 8) m = fmaxf(m, sS[qq * 33 + k]);
        m = fmaxf(m, __shfl_xor(m, 1));
        m = fmaxf(m, __shfl_xor(m, 2));
        m = fmaxf(m, __shfl_xor(m, 4));
        float sum = 0.f;
        for (int qq = sub; qq < Q_N; qq += 8) {
            float e = __expf(sS[qq * 33 + k] - m);  // all-masked column: exp(0)=1 -> 1/196
            sS[qq * 33 + k] = e;
            sum += e;
        }
        sum += __shfl_xor(sum, 1);
        sum += __shfl_xor(sum, 2);
        sum += __shfl_xor(sum, 4);
        float r = 1.0f / sum;
        for (int qq = sub; qq < Q_N; qq += 8) sS[qq * 33 + k] *= r;
    }
    __syncthreads();

    // coalesced write of text_attention
    {
        float* tbase = tattn_out + (size_t)bid * (Q_N * K_N);
        for (int j = tid; j < Q_N * K_N; j += 256) {
            int qq = j >> 5, k = j & 31;
            tbase[j] = sS[qq * 33 + k];
        }
    }

    // PV: o[d] = sum_k a[k] * V[k,d]
    float4 o4[16];
#pragma unroll
    for (int j = 0; j < 16; ++j) o4[j] = make_float4(0.f, 0.f, 0.f, 0.f);
    if (active) {
#pragma unroll
        for (int k = 0; k < K_N; ++k) {
            float a = s[k];
#pragma unroll
            for (int j = 0; j < 16; ++j) {
                float4 v = sVf4[k * 16 + j];
                o4[j].x += a * v.x; o4[j].y += a * v.y;
                o4[j].z += a * v.z; o4[j].w += a * v.w;
            }
        }
    }
    // reduce o over q (all threads participate; inactive contribute zeros)
#pragma unroll
    for (int j = 0; j < 16; ++j) {
        float vx = o4[j].x, vy = o4[j].y, vz = o4[j].z, vw = o4[j].w;
#pragma unroll
        for (int sh = 1; sh < 64; sh <<= 1) {
            vx += __shfl_xor(vx, sh);
            vy += __shfl_xor(vy, sh);
            vz += __shfl_xor(vz, sh);
            vw += __shfl_xor(vw, sh);
        }
        if ((tid & 63) == 0) {
            atomicAdd(&sPool[j * 4 + 0], vx);
            atomicAdd(&sPool[j * 4 + 1], vy);
            atomicAdd(&sPool[j * 4 + 2], vz);
            atomicAdd(&sPool[j * 4 + 3], vw);
        }
    }
    __syncthreads();
    if (tid < 64) pooled[((size_t)(i * T_N + t)) * E_N + h * 64 + tid] = sPool[tid];
}

// ---------------------------------------------------------------------------
// fc_out on POOLED rows (mean commutes with the linear layer):
// out[p, f] = bo[f] + (1/196) * sum_e pooledSum[p, e] * Wo[f, e]
__global__ __launch_bounds__(256) void fc_out_kernel(const float* __restrict__ pooled,
                                                     const float* __restrict__ Wo,
                                                     const float* __restrict__ bo,
                                                     float* __restrict__ out) {
    __shared__ float sP[4 * 512];
    int tid = threadIdx.x;
    int p0 = blockIdx.x * 4;
    for (int j = tid; j < 2048; j += 256) sP[j] = pooled[(size_t)p0 * 512 + j];
    __syncthreads();
    const float4* sPf4 = (const float4*)sP;
    const float4* Wof4 = (const float4*)Wo;
    int f0 = tid, f1 = tid + 256;
    float acc0[4] = {0.f, 0.f, 0.f, 0.f};
    float acc1[4] = {0.f, 0.f, 0.f, 0.f};
    for (int e4 = 0; e4 < 128; ++e4) {
        float4 w0 = Wof4[f0 * 128 + e4];
        float4 w1 = Wof4[f1 * 128 + e4];
#pragma unroll
        for (int j = 0; j < 4; ++j) {
            float4 p = sPf4[j * 128 + e4];
            acc0[j] += p.x * w0.x + p.y * w0.y + p.z * w0.z + p.w * w0.w;
            acc1[j] += p.x * w1.x + p.y * w1.y + p.z * w1.z + p.w * w1.w;
        }
    }
    const float invQ = 1.0f / 196.0f;
    float b0 = bo[f0], b1 = bo[f1];
#pragma unroll
    for (int j = 0; j < 4; ++j) {
        out[(size_t)(p0 + j) * 512 + f0] = b0 + acc0[j] * invQ;
        out[(size_t)(p0 + j) * 512 + f1] = b1 + acc1[j] * invQ;
    }
}

// ---------------------------------------------------------------------------
extern "C" void kernel_launch(void* const* d_in, const int* in_sizes, int n_in,
                              void* d_out, int out_size, void* d_ws, size_t ws_size,
                              hipStream_t stream) {
    const float* image = (const float*)d_in[0];
    const float* text  = (const float*)d_in[1];
    const int*   mask  = (const int*)d_in[2];
    const float* Wq    = (const float*)d_in[3];
    const float* Wk    = (const float*)d_in[4];
    const float* Wv    = (const float*)d_in[5];
    const float* Wo    = (const float*)d_in[6];
    const float* bo    = (const float*)d_in[7];
    float* out = (float*)d_out;

    // workspace layout (floats): qproj | kproj | vproj | pooledSum | maskMode
    float* qproj  = (float*)d_ws;                 // I*Q*H*D = 1,605,632
    float* kproj  = qproj + (size_t)I_N * Q_N * H_N * D_N;   // T*K*H*D = 1,048,576
    float* vproj  = kproj + (size_t)T_N * K_N * H_N * D_N;
    float* pooled = vproj + (size_t)T_N * K_N * H_N * D_N;   // I*T*E = 524,288
    int*   mode   = (int*)(pooled + (size_t)I_N * T_N * E_N);

    float* attn  = out + (size_t)I_N * T_N * E_N;
    float* tattn = attn + (size_t)I_N * T_N * H_N * Q_N * K_N;

    detect_mask_kernel<<<1, 512, 0, stream>>>((const unsigned int*)mask, mode);
    proj_q_kernel<<<(I_N * Q_N * H_N) / 4, 256, 0, stream>>>(image, Wq, qproj);
    proj_kv_kernel<<<(T_N * K_N * H_N) / 4, 256, 0, stream>>>(text, Wk, Wv, kproj, vproj);
    attn_kernel<<<I_N * T_N * H_N, 256, 0, stream>>>(qproj, kproj, vproj, mask, mode,
                                                     attn, tattn, pooled);
    fc_out_kernel<<<(I_N * T_N) / 4, 256, 0, stream>>>(pooled, Wo, bo, out);
}

// Round 2
// 745.758 us; speedup vs baseline: 1.9023x; 1.9023x over previous
//
#include <hip/hip_runtime.h>
#include <math.h>

// Problem dims
#define I_N 16
#define T_N 64
#define Q_N 196
#define K_N 32
#define E_N 512
#define H_N 8
#define D_N 64

// finfo(f32).min / sqrt(512) -- masked entries AFTER the /sqrt(E) scaling.
// Finite and identical for all masked entries => column softmax of a fully
// masked (t,k) column gives exactly uniform 1/196 (matches jax reference).
#define NEG_MASKED (-1.5038454e37f)
#define INV_SQRT_E (0.044194173824159216f)  // 1/sqrt(512)

// ---------------------------------------------------------------------------
// Mask dtype detection: bool may arrive as int32 {0,1}, float {0.f,1.f}, or
// packed bytes. mode 0 = int32, 1 = float32, 2 = bytes
__global__ __launch_bounds__(512) void detect_mask_kernel(const unsigned int* __restrict__ mask,
                                                          int* __restrict__ flag) {
    __shared__ int notSimple, sawFloat;
    int tid = threadIdx.x;
    if (tid == 0) { notSimple = 0; sawFloat = 0; }
    __syncthreads();
    unsigned int v = mask[tid];
    if (v != 0u && v != 1u && v != 0x3f800000u) atomicOr(&notSimple, 1);
    if (v == 0x3f800000u) atomicOr(&sawFloat, 1);
    __syncthreads();
    if (tid == 0) flag[0] = notSimple ? 2 : (sawFloat ? 1 : 0);
}

// ---------------------------------------------------------------------------
// query projection -> layout [i][h][q][d] (head-major so attn reads of a
// (i,h) Q-tile are contiguous). out[((i*H+h)*Q+q)*64+n] = sum_d x[r,d]*W[n,d]
__global__ __launch_bounds__(256) void proj_q_kernel(const float* __restrict__ x,
                                                     const float* __restrict__ W,
                                                     float* __restrict__ out) {
    __shared__ float sWt[64 * 65];
    __shared__ float sX[256];
    int tid = threadIdx.x;
    for (int j = tid; j < 4096; j += 256) {
        int n = j >> 6, d = j & 63;
        sWt[d * 65 + n] = W[j];
    }
    int rowBase = blockIdx.x * 4;
    sX[tid] = x[rowBase * 64 + tid];
    __syncthreads();
    int wave = tid >> 6, lane = tid & 63;
    float acc = 0.f;
#pragma unroll
    for (int d = 0; d < 64; ++d) acc += sX[wave * 64 + d] * sWt[d * 65 + lane];
    int r = rowBase + wave;                 // r = (i*Q + q)*H + h
    int i = r / (Q_N * H_N);
    int rem = r - i * (Q_N * H_N);
    int q = rem >> 3, h = rem & 7;
    out[(((size_t)i * H_N + h) * Q_N + q) * 64 + lane] = acc;
}

// key + value projection -> layout [t][h][k][d]
__global__ __launch_bounds__(256) void proj_kv_kernel(const float* __restrict__ x,
                                                      const float* __restrict__ Wk,
                                                      const float* __restrict__ Wv,
                                                      float* __restrict__ kout,
                                                      float* __restrict__ vout) {
    __shared__ float sWkT[64 * 65];
    __shared__ float sWvT[64 * 65];
    __shared__ float sX[256];
    int tid = threadIdx.x;
    for (int j = tid; j < 4096; j += 256) {
        int n = j >> 6, d = j & 63;
        sWkT[d * 65 + n] = Wk[j];
        sWvT[d * 65 + n] = Wv[j];
    }
    int rowBase = blockIdx.x * 4;
    sX[tid] = x[rowBase * 64 + tid];
    __syncthreads();
    int wave = tid >> 6, lane = tid & 63;
    float ak = 0.f, av = 0.f;
#pragma unroll
    for (int d = 0; d < 64; ++d) {
        float xv = sX[wave * 64 + d];
        ak += xv * sWkT[d * 65 + lane];
        av += xv * sWvT[d * 65 + lane];
    }
    int r = rowBase + wave;                 // r = (t*K + k)*H + h
    int t = r >> 8;
    int rem = r & 255;
    int k = rem >> 3, h = rem & 7;
    size_t dst = (((size_t)t * H_N + h) * K_N + k) * 64 + lane;
    kout[dst] = ak;
    vout[dst] = av;
}

// ---------------------------------------------------------------------------
// Main attention kernel. One block per (i, t, h). 256 threads; thread = q row.
// PV GEMM eliminated: mean_q(A@V) = (colsum_q A) @ V / 196 -- pooled needs
// only the attention column-sums, recomputed from stored row stats during
// the column-softmax pass.
__global__ __launch_bounds__(256) void attn_kernel(const float* __restrict__ qproj,
                                                   const float* __restrict__ kproj,
                                                   const float* __restrict__ vproj,
                                                   const int* __restrict__ mask,
                                                   const int* __restrict__ modeFlag,
                                                   float* __restrict__ attn_out,
                                                   float* __restrict__ tattn_out,
                                                   float* __restrict__ pooled) {
    __shared__ float sK[K_N * 64];          //  8 KB
    __shared__ float sS[Q_N * 33];          // 25.9 KB, stride 33: conflict-free
    __shared__ float sMrow[Q_N];            // row max
    __shared__ float sRrow[Q_N];            // row 1/sum
    __shared__ float sColRed[8 * 32];       // cross-sub partials
    __shared__ float sColRed2[8 * 32];
    __shared__ float sColMax[32];
    __shared__ float sColR[32];             // 1/colsum(e)
    __shared__ float sCa[32];               // colsum of row-softmaxed A
    __shared__ float sMask[K_N];

    int tid = threadIdx.x;
    int bid = blockIdx.x;
    int h = bid & 7;
    int t = (bid >> 3) & 63;
    int i = bid >> 9;

    // K tile: contiguous 8 KB in [t][h][k][d] layout
    {
        const float4* src = (const float4*)(kproj + ((size_t)t * H_N + h) * (K_N * 64));
        float4* dst = (float4*)sK;
        dst[tid] = src[tid];
        dst[tid + 256] = src[tid + 256];
    }
    int mode = modeFlag[0];
    if (tid < K_N) {
        int idx = t * K_N + tid;
        bool keep;
        if (mode == 2)      keep = ((const unsigned char*)mask)[idx] != 0;
        else if (mode == 1) keep = ((const float*)mask)[idx] != 0.0f;
        else                keep = mask[idx] != 0;
        sMask[tid] = keep ? 1.0f : 0.0f;
    }
    __syncthreads();

    const float4* sKf4 = (const float4*)sK;
    int q = tid;
    bool active = (q < Q_N);
    float s[K_N];

    if (active) {
#pragma unroll
        for (int k = 0; k < K_N; ++k) s[k] = 0.f;
        const float4* qrow = (const float4*)(qproj + (((size_t)i * H_N + h) * Q_N + q) * 64);
#pragma unroll
        for (int d4o = 0; d4o < 4; ++d4o) {
            float4 qv0 = qrow[d4o * 4 + 0];
            float4 qv1 = qrow[d4o * 4 + 1];
            float4 qv2 = qrow[d4o * 4 + 2];
            float4 qv3 = qrow[d4o * 4 + 3];
#pragma unroll
            for (int k = 0; k < K_N; ++k) {
                float4 k0 = sKf4[k * 16 + d4o * 4 + 0];
                float4 k1 = sKf4[k * 16 + d4o * 4 + 1];
                float4 k2 = sKf4[k * 16 + d4o * 4 + 2];
                float4 k3 = sKf4[k * 16 + d4o * 4 + 3];
                s[k] += qv0.x * k0.x + qv0.y * k0.y + qv0.z * k0.z + qv0.w * k0.w
                      + qv1.x * k1.x + qv1.y * k1.y + qv1.z * k1.z + qv1.w * k1.w
                      + qv2.x * k2.x + qv2.y * k2.y + qv2.z * k2.z + qv2.w * k2.w
                      + qv3.x * k3.x + qv3.y * k3.y + qv3.z * k3.z + qv3.w * k3.w;
            }
        }
        float m = -INFINITY;
#pragma unroll
        for (int k = 0; k < K_N; ++k) {
            float v = (sMask[k] != 0.f) ? s[k] * INV_SQRT_E : NEG_MASKED;
            s[k] = v;
            sS[q * 33 + k] = v;               // bank (q+k)%32: 2-way, free
            m = fmaxf(m, v);
        }
        float sum = 0.f;
#pragma unroll
        for (int k = 0; k < K_N; ++k) {
            float e = __expf(s[k] - m);       // masked: exp(-1.5e37) -> 0
            s[k] = e;
            sum += e;
        }
        float r = 1.0f / sum;
        sMrow[q] = m;
        sRrow[q] = r;
#pragma unroll
        for (int k = 0; k < K_N; ++k) s[k] *= r;
        // attention row write: 32 consecutive floats
        float4* arow = (float4*)(attn_out + (size_t)bid * (Q_N * K_N) + q * K_N);
#pragma unroll
        for (int k4 = 0; k4 < 8; ++k4) {
            float4 v;
            v.x = s[k4 * 4 + 0]; v.y = s[k4 * 4 + 1];
            v.z = s[k4 * 4 + 2]; v.w = s[k4 * 4 + 3];
            arow[k4] = v;
        }
    }
    __syncthreads();

    // ---- column softmax over q + attention colsum, k = tid&31 (bank-free) --
    int kc = tid & 31, sub = tid >> 5;
    {
        float m = -INFINITY;
        for (int qq = sub; qq < Q_N; qq += 8) m = fmaxf(m, sS[qq * 33 + kc]);
        sColRed[sub * 32 + kc] = m;
    }
    __syncthreads();
    if (tid < 32) {
        float mm = sColRed[tid];
#pragma unroll
        for (int s2 = 1; s2 < 8; ++s2) mm = fmaxf(mm, sColRed[s2 * 32 + tid]);
        sColMax[tid] = mm;
    }
    __syncthreads();
    {
        float mcol = sColMax[kc];
        float csum = 0.f, casum = 0.f;
        for (int qq = sub; qq < Q_N; qq += 8) {
            float v = sS[qq * 33 + kc];
            float e = __expf(v - mcol);       // all-masked col: exp(0)=1 -> 1/196
            sS[qq * 33 + kc] = e;
            csum += e;
            casum += __expf(v - sMrow[qq]) * sRrow[qq];  // row-softmax prob
        }
        sColRed[sub * 32 + kc] = csum;
        sColRed2[sub * 32 + kc] = casum;
    }
    __syncthreads();
    if (tid < 32) {
        float s1 = 0.f, s2v = 0.f;
#pragma unroll
        for (int s2 = 0; s2 < 8; ++s2) {
            s1 += sColRed[s2 * 32 + tid];
            s2v += sColRed2[s2 * 32 + tid];
        }
        sColR[tid] = 1.0f / s1;
        sCa[tid] = s2v;
    }
    __syncthreads();

    // coalesced write of text_attention (normalize on the fly)
    {
        float* tbase = tattn_out + (size_t)bid * (Q_N * K_N);
        for (int j = tid; j < Q_N * K_N; j += 256) {
            int qq = j >> 5, k = j & 31;
            tbase[j] = sS[qq * 33 + k] * sColR[k];
        }
    }

    // pooled SUM over q of (A@V):  pooled[d] = sum_k colsum_a[k] * V[k,d]
    if (tid < 64) {
        const float* vb = vproj + ((size_t)t * H_N + h) * (K_N * 64) + tid;
        float acc = 0.f;
#pragma unroll
        for (int k = 0; k < K_N; ++k) acc += sCa[k] * vb[k * 64];
        pooled[((size_t)(i * T_N + t)) * E_N + h * 64 + tid] = acc;
    }
}

// ---------------------------------------------------------------------------
// fc_out on POOLED rows (mean commutes with the linear layer):
// out[p, f] = bo[f] + (1/196) * sum_e pooledSum[p, e] * Wo[f, e]
// grid (I*T/4, 2): block = 4 rows x 256 f-columns
__global__ __launch_bounds__(256) void fc_out_kernel(const float* __restrict__ pooled,
                                                     const float* __restrict__ Wo,
                                                     const float* __restrict__ bo,
                                                     float* __restrict__ out) {
    __shared__ float sP[4 * 512];
    int tid = threadIdx.x;
    int p0 = blockIdx.x * 4;
    {
        const float4* src = (const float4*)(pooled + (size_t)p0 * 512);
        float4* dst = (float4*)sP;
        dst[tid] = src[tid];
        dst[tid + 256] = src[tid + 256];
    }
    __syncthreads();
    const float4* sPf4 = (const float4*)sP;
    const float4* Wof4 = (const float4*)Wo;
    int f = blockIdx.y * 256 + tid;
    float acc[4] = {0.f, 0.f, 0.f, 0.f};
    for (int e4 = 0; e4 < 128; ++e4) {
        float4 w = Wof4[f * 128 + e4];
#pragma unroll
        for (int j = 0; j < 4; ++j) {
            float4 p = sPf4[j * 128 + e4];
            acc[j] += p.x * w.x + p.y * w.y + p.z * w.z + p.w * w.w;
        }
    }
    const float invQ = 1.0f / 196.0f;
    float b = bo[f];
#pragma unroll
    for (int j = 0; j < 4; ++j)
        out[(size_t)(p0 + j) * 512 + f] = b + acc[j] * invQ;
}

// ---------------------------------------------------------------------------
extern "C" void kernel_launch(void* const* d_in, const int* in_sizes, int n_in,
                              void* d_out, int out_size, void* d_ws, size_t ws_size,
                              hipStream_t stream) {
    const float* image = (const float*)d_in[0];
    const float* text  = (const float*)d_in[1];
    const int*   mask  = (const int*)d_in[2];
    const float* Wq    = (const float*)d_in[3];
    const float* Wk    = (const float*)d_in[4];
    const float* Wv    = (const float*)d_in[5];
    const float* Wo    = (const float*)d_in[6];
    const float* bo    = (const float*)d_in[7];
    float* out = (float*)d_out;

    // workspace layout (floats): qproj | kproj | vproj | pooledSum | maskMode
    float* qproj  = (float*)d_ws;                            // I*H*Q*D
    float* kproj  = qproj + (size_t)I_N * Q_N * H_N * D_N;   // T*H*K*D
    float* vproj  = kproj + (size_t)T_N * K_N * H_N * D_N;
    float* pooled = vproj + (size_t)T_N * K_N * H_N * D_N;   // I*T*E
    int*   mode   = (int*)(pooled + (size_t)I_N * T_N * E_N);

    float* attn  = out + (size_t)I_N * T_N * E_N;
    float* tattn = attn + (size_t)I_N * T_N * H_N * Q_N * K_N;

    detect_mask_kernel<<<1, 512, 0, stream>>>((const unsigned int*)mask, mode);
    proj_q_kernel<<<(I_N * Q_N * H_N) / 4, 256, 0, stream>>>(image, Wq, qproj);
    proj_kv_kernel<<<(T_N * K_N * H_N) / 4, 256, 0, stream>>>(text, Wk, Wv, kproj, vproj);
    attn_kernel<<<I_N * T_N * H_N, 256, 0, stream>>>(qproj, kproj, vproj, mask, mode,
                                                     attn, tattn, pooled);
    fc_out_kernel<<<dim3((I_N * T_N) / 4, 2), 256, 0, stream>>>(pooled, Wo, bo, out);
}

// Round 3
// 561.305 us; speedup vs baseline: 2.5275x; 1.3286x over previous
//
#include <hip/hip_runtime.h>
#include <math.h>

// Problem dims
#define I_N 16
#define T_N 64
#define Q_N 196
#define K_N 32
#define E_N 512
#define H_N 8
#define D_N 64

// finfo(f32).min / sqrt(512) -- masked entries AFTER the /sqrt(E) scaling.
#define NEG_MASKED (-1.5038454e37f)
#define INV_SQRT_E (0.044194173824159216f)  // 1/sqrt(512)

typedef __attribute__((ext_vector_type(8))) short bf16x8;
typedef __attribute__((ext_vector_type(4))) float f32x4;

// round-to-nearest-even fp32 -> bf16 (bit pattern in short)
__device__ __forceinline__ short f2bf(float x) {
    unsigned u = __builtin_bit_cast(unsigned, x);
    unsigned r = (u + 0x7fffu + ((u >> 16) & 1u)) >> 16;
    return (short)r;
}
__device__ __forceinline__ float bf2f(short s) {
    unsigned u = ((unsigned)(unsigned short)s) << 16;
    return __builtin_bit_cast(float, u);
}
// split 8 consecutive floats into hi/lo bf16 fragments
__device__ __forceinline__ void cvt8(float4 a, float4 b, bf16x8& hi, bf16x8& lo) {
    float xs[8] = {a.x, a.y, a.z, a.w, b.x, b.y, b.z, b.w};
#pragma unroll
    for (int j = 0; j < 8; ++j) {
        short h = f2bf(xs[j]);
        hi[j] = h;
        lo[j] = f2bf(xs[j] - bf2f(h));
    }
}

// ---------------------------------------------------------------------------
// Mask dtype detection: mode 0 = int32, 1 = float32, 2 = bytes
__global__ __launch_bounds__(512) void detect_mask_kernel(const unsigned int* __restrict__ mask,
                                                          int* __restrict__ flag) {
    __shared__ int notSimple, sawFloat;
    int tid = threadIdx.x;
    if (tid == 0) { notSimple = 0; sawFloat = 0; }
    __syncthreads();
    unsigned int v = mask[tid];
    if (v != 0u && v != 1u && v != 0x3f800000u) atomicOr(&notSimple, 1);
    if (v == 0x3f800000u) atomicOr(&sawFloat, 1);
    __syncthreads();
    if (tid == 0) flag[0] = notSimple ? 2 : (sawFloat ? 1 : 0);
}

// ---------------------------------------------------------------------------
// query projection -> layout [i][h][q][d]; 16 rows/block (W staging amortized)
__global__ __launch_bounds__(256) void proj_q_kernel(const float* __restrict__ x,
                                                     const float* __restrict__ W,
                                                     float* __restrict__ out) {
    __shared__ float sWt[64 * 65];
    __shared__ float sX[16 * 64];
    int tid = threadIdx.x;
    for (int j = tid; j < 4096; j += 256) {
        int n = j >> 6, d = j & 63;
        sWt[d * 65 + n] = W[j];
    }
    int rowBase = blockIdx.x * 16;
    for (int j = tid; j < 1024; j += 256) sX[j] = x[rowBase * 64 + j];
    __syncthreads();
    int wave = tid >> 6, lane = tid & 63;
    float acc[4] = {0.f, 0.f, 0.f, 0.f};
    for (int d = 0; d < 64; ++d) {
        float w = sWt[d * 65 + lane];
#pragma unroll
        for (int j = 0; j < 4; ++j) acc[j] += sX[(wave * 4 + j) * 64 + d] * w;
    }
#pragma unroll
    for (int j = 0; j < 4; ++j) {
        int r = rowBase + wave * 4 + j;     // r = (i*Q + q)*H + h
        int i = r / (Q_N * H_N);
        int rem = r - i * (Q_N * H_N);
        int q = rem >> 3, h = rem & 7;
        out[(((size_t)i * H_N + h) * Q_N + q) * 64 + lane] = acc[j];
    }
}

// key + value projection -> layout [t][h][k][d]; 16 rows/block
__global__ __launch_bounds__(256) void proj_kv_kernel(const float* __restrict__ x,
                                                      const float* __restrict__ Wk,
                                                      const float* __restrict__ Wv,
                                                      float* __restrict__ kout,
                                                      float* __restrict__ vout) {
    __shared__ float sWkT[64 * 65];
    __shared__ float sWvT[64 * 65];
    __shared__ float sX[16 * 64];
    int tid = threadIdx.x;
    for (int j = tid; j < 4096; j += 256) {
        int n = j >> 6, d = j & 63;
        sWkT[d * 65 + n] = Wk[j];
        sWvT[d * 65 + n] = Wv[j];
    }
    int rowBase = blockIdx.x * 16;
    for (int j = tid; j < 1024; j += 256) sX[j] = x[rowBase * 64 + j];
    __syncthreads();
    int wave = tid >> 6, lane = tid & 63;
    float ak[4] = {0.f, 0.f, 0.f, 0.f};
    float av[4] = {0.f, 0.f, 0.f, 0.f};
    for (int d = 0; d < 64; ++d) {
        float wk = sWkT[d * 65 + lane];
        float wv = sWvT[d * 65 + lane];
#pragma unroll
        for (int j = 0; j < 4; ++j) {
            float xv = sX[(wave * 4 + j) * 64 + d];
            ak[j] += xv * wk;
            av[j] += xv * wv;
        }
    }
#pragma unroll
    for (int j = 0; j < 4; ++j) {
        int r = rowBase + wave * 4 + j;     // r = (t*K + k)*H + h
        int t = r >> 8;
        int rem = r & 255;
        int k = rem >> 3, h = rem & 7;
        size_t dst = (((size_t)t * H_N + h) * K_N + k) * 64 + lane;
        kout[dst] = ak[j];
        vout[dst] = av[j];
    }
}

// ---------------------------------------------------------------------------
// Wo transpose: WoT[e][f] = Wo[f][e], so fc_out reads are lane-coalesced
__global__ __launch_bounds__(256) void transpose_wo_kernel(const float* __restrict__ Wo,
                                                           float* __restrict__ WoT) {
    __shared__ float tile[32][33];
    int tx = threadIdx.x & 31, ty = threadIdx.x >> 5;   // ty 0..7
    int e0 = blockIdx.x * 32, f0 = blockIdx.y * 32;
#pragma unroll
    for (int k = 0; k < 4; ++k) {
        int fy = ty + k * 8;
        tile[fy][tx] = Wo[(size_t)(f0 + fy) * E_N + e0 + tx];
    }
    __syncthreads();
#pragma unroll
    for (int k = 0; k < 4; ++k) {
        int ey = ty + k * 8;
        WoT[(size_t)(e0 + ey) * E_N + f0 + tx] = tile[tx][ey];
    }
}

// ---------------------------------------------------------------------------
// Main attention kernel. One block per (i,t,h); 4 waves.
// QK^T via mfma_f32_16x16x32_bf16 with bf16 hi/lo split (fp32-grade):
//   A frag: lane holds Q[m=lane&15][k=quad*8+j]  -> 8 consecutive d floats
//   B frag: lane holds K[n=lane&15][k=quad*8+j]  -> 8 consecutive d floats
//   C frag: col=lane&15, row=quad*4+reg
// Row softmax done in-register with 16-lane butterflies; col softmax in LDS.
__global__ __launch_bounds__(256) void attn_kernel(const float* __restrict__ qproj,
                                                   const float* __restrict__ kproj,
                                                   const float* __restrict__ vproj,
                                                   const int* __restrict__ mask,
                                                   const int* __restrict__ modeFlag,
                                                   float* __restrict__ attn_out,
                                                   float* __restrict__ tattn_out,
                                                   float* __restrict__ pooled) {
    __shared__ float sS[Q_N * 33];          // scaled+masked scores, bank-free
    __shared__ float sMrow[Q_N];            // row max
    __shared__ float sRrow[Q_N];            // row 1/sum
    __shared__ float sColRed[8 * 32];
    __shared__ float sColRed2[8 * 32];
    __shared__ float sColMax[32];
    __shared__ float sColR[32];
    __shared__ float sCa[32];               // colsum of row-softmaxed A
    __shared__ float sMask[K_N];

    int tid = threadIdx.x;
    int bid = blockIdx.x;
    int h = bid & 7;
    int t = (bid >> 3) & 63;
    int i = bid >> 9;
    int lane = tid & 63, wave = tid >> 6;
    int quad = lane >> 4, lid = lane & 15;

    int mode = modeFlag[0];
    if (tid < K_N) {
        int idx = t * K_N + tid;
        bool keep;
        if (mode == 2)      keep = ((const unsigned char*)mask)[idx] != 0;
        else if (mode == 1) keep = ((const float*)mask)[idx] != 0.0f;
        else                keep = mask[idx] != 0;
        sMask[tid] = keep ? 1.0f : 0.0f;
    }
    __syncthreads();

    // B fragments (K^T) straight from global: [ntile][kstep], hi+lo
    const float* kb = kproj + ((size_t)t * H_N + h) * (K_N * 64);
    bf16x8 Bh[2][2], Bl[2][2];
#pragma unroll
    for (int nt = 0; nt < 2; ++nt)
#pragma unroll
        for (int ks = 0; ks < 2; ++ks) {
            const float* p = kb + (nt * 16 + lid) * 64 + ks * 32 + quad * 8;
            cvt8(*(const float4*)p, *(const float4*)(p + 4), Bh[nt][ks], Bl[nt][ks]);
        }

    const float* qbh = qproj + ((size_t)i * H_N + h) * (Q_N * 64);
    float keep0 = sMask[lid], keep1 = sMask[16 + lid];

    for (int mt = wave; mt < 13; mt += 4) {
        int qbase = mt * 16;
        int qr = qbase + lid; if (qr > Q_N - 1) qr = Q_N - 1;   // clamp pad rows
        const float* ab = qbh + (size_t)qr * 64 + quad * 8;
        bf16x8 Ah0, Al0, Ah1, Al1;
        cvt8(*(const float4*)ab, *(const float4*)(ab + 4), Ah0, Al0);
        cvt8(*(const float4*)(ab + 32), *(const float4*)(ab + 36), Ah1, Al1);

        f32x4 acc0 = {0.f, 0.f, 0.f, 0.f}, acc1 = {0.f, 0.f, 0.f, 0.f};
        // ntile 0: hi*lo + lo*hi + hi*hi  (kstep 0 then 1)
        acc0 = __builtin_amdgcn_mfma_f32_16x16x32_bf16(Al0, Bh[0][0], acc0, 0, 0, 0);
        acc0 = __builtin_amdgcn_mfma_f32_16x16x32_bf16(Ah0, Bl[0][0], acc0, 0, 0, 0);
        acc0 = __builtin_amdgcn_mfma_f32_16x16x32_bf16(Ah0, Bh[0][0], acc0, 0, 0, 0);
        acc0 = __builtin_amdgcn_mfma_f32_16x16x32_bf16(Al1, Bh[0][1], acc0, 0, 0, 0);
        acc0 = __builtin_amdgcn_mfma_f32_16x16x32_bf16(Ah1, Bl[0][1], acc0, 0, 0, 0);
        acc0 = __builtin_amdgcn_mfma_f32_16x16x32_bf16(Ah1, Bh[0][1], acc0, 0, 0, 0);
        // ntile 1
        acc1 = __builtin_amdgcn_mfma_f32_16x16x32_bf16(Al0, Bh[1][0], acc1, 0, 0, 0);
        acc1 = __builtin_amdgcn_mfma_f32_16x16x32_bf16(Ah0, Bl[1][0], acc1, 0, 0, 0);
        acc1 = __builtin_amdgcn_mfma_f32_16x16x32_bf16(Ah0, Bh[1][0], acc1, 0, 0, 0);
        acc1 = __builtin_amdgcn_mfma_f32_16x16x32_bf16(Al1, Bh[1][1], acc1, 0, 0, 0);
        acc1 = __builtin_amdgcn_mfma_f32_16x16x32_bf16(Ah1, Bl[1][1], acc1, 0, 0, 0);
        acc1 = __builtin_amdgcn_mfma_f32_16x16x32_bf16(Ah1, Bh[1][1], acc1, 0, 0, 0);

        float mrow[4], rrow[4];
#pragma unroll
        for (int reg = 0; reg < 4; ++reg) {
            float s0 = keep0 != 0.f ? acc0[reg] * INV_SQRT_E : NEG_MASKED;
            float s1 = keep1 != 0.f ? acc1[reg] * INV_SQRT_E : NEG_MASKED;
            float pm = fmaxf(s0, s1);
            pm = fmaxf(pm, __shfl_xor(pm, 1));
            pm = fmaxf(pm, __shfl_xor(pm, 2));
            pm = fmaxf(pm, __shfl_xor(pm, 4));
            pm = fmaxf(pm, __shfl_xor(pm, 8));
            float e0 = __expf(s0 - pm), e1 = __expf(s1 - pm);
            float ps = e0 + e1;
            ps += __shfl_xor(ps, 1);
            ps += __shfl_xor(ps, 2);
            ps += __shfl_xor(ps, 4);
            ps += __shfl_xor(ps, 8);
            float r = 1.0f / ps;
            mrow[reg] = pm; rrow[reg] = r;
            int q = qbase + quad * 4 + reg;
            if (q < Q_N) {
                float* arow = attn_out + (size_t)bid * (Q_N * K_N) + q * K_N;
                arow[lid] = e0 * r;
                arow[16 + lid] = e1 * r;
                sS[q * 33 + lid] = s0;
                sS[q * 33 + 16 + lid] = s1;
            }
        }
        if (lid == 0) {
#pragma unroll
            for (int reg = 0; reg < 4; ++reg) {
                int q = qbase + quad * 4 + reg;
                if (q < Q_N) { sMrow[q] = mrow[reg]; sRrow[q] = rrow[reg]; }
            }
        }
    }
    __syncthreads();

    // ---- column softmax over q + attention colsum, k = tid&31 (bank-free) --
    int kc = tid & 31, sub = tid >> 5;
    {
        float m = -INFINITY;
        for (int qq = sub; qq < Q_N; qq += 8) m = fmaxf(m, sS[qq * 33 + kc]);
        sColRed[sub * 32 + kc] = m;
    }
    __syncthreads();
    if (tid < 32) {
        float mm = sColRed[tid];
#pragma unroll
        for (int s2 = 1; s2 < 8; ++s2) mm = fmaxf(mm, sColRed[s2 * 32 + tid]);
        sColMax[tid] = mm;
    }
    __syncthreads();
    {
        float mcol = sColMax[kc];
        float csum = 0.f, casum = 0.f;
        for (int qq = sub; qq < Q_N; qq += 8) {
            float v = sS[qq * 33 + kc];
            float e = __expf(v - mcol);       // all-masked col: exp(0)=1 -> 1/196
            sS[qq * 33 + kc] = e;
            csum += e;
            casum += __expf(v - sMrow[qq]) * sRrow[qq];
        }
        sColRed[sub * 32 + kc] = csum;
        sColRed2[sub * 32 + kc] = casum;
    }
    __syncthreads();
    if (tid < 32) {
        float s1 = 0.f, s2v = 0.f;
#pragma unroll
        for (int s2 = 0; s2 < 8; ++s2) {
            s1 += sColRed[s2 * 32 + tid];
            s2v += sColRed2[s2 * 32 + tid];
        }
        sColR[tid] = 1.0f / s1;
        sCa[tid] = s2v;
    }
    __syncthreads();

    // coalesced write of text_attention (normalize on the fly)
    {
        float* tbase = tattn_out + (size_t)bid * (Q_N * K_N);
        for (int j = tid; j < Q_N * K_N; j += 256) {
            int qq = j >> 5, k = j & 31;
            tbase[j] = sS[qq * 33 + k] * sColR[k];
        }
    }

    // pooled SUM over q of (A@V):  pooled[d] = sum_k colsum_a[k] * V[k,d]
    if (tid < 64) {
        const float* vb = vproj + ((size_t)t * H_N + h) * (K_N * 64) + tid;
        float acc = 0.f;
#pragma unroll
        for (int k = 0; k < K_N; ++k) acc += sCa[k] * vb[k * 64];
        pooled[((size_t)(i * T_N + t)) * E_N + h * 64 + tid] = acc;
    }
}

// ---------------------------------------------------------------------------
// fc_out on POOLED rows: out[p,f] = bo[f] + (1/196) * sum_e P[p,e]*WoT[e,f]
// P staged transposed (sPT4[e] = one b128 read); WoT reads lane-coalesced.
__global__ __launch_bounds__(256) void fc_out_kernel(const float* __restrict__ pooled,
                                                     const float* __restrict__ WoT,
                                                     const float* __restrict__ bo,
                                                     float* __restrict__ out) {
    __shared__ float sPT[E_N * 4];
    int tid = threadIdx.x;
    int p0 = blockIdx.x * 4;
#pragma unroll
    for (int j = 0; j < 4; ++j) {
        sPT[tid * 4 + j] = pooled[(size_t)(p0 + j) * E_N + tid];
        sPT[(256 + tid) * 4 + j] = pooled[(size_t)(p0 + j) * E_N + 256 + tid];
    }
    __syncthreads();
    const float4* sPT4 = (const float4*)sPT;
    int f = blockIdx.y * 256 + tid;
    float4 acc = make_float4(0.f, 0.f, 0.f, 0.f);
    for (int e = 0; e < E_N; e += 2) {
        float w0 = WoT[(size_t)e * E_N + f];
        float w1 = WoT[(size_t)(e + 1) * E_N + f];
        float4 pv0 = sPT4[e];
        float4 pv1 = sPT4[e + 1];
        acc.x += pv0.x * w0 + pv1.x * w1;
        acc.y += pv0.y * w0 + pv1.y * w1;
        acc.z += pv0.z * w0 + pv1.z * w1;
        acc.w += pv0.w * w0 + pv1.w * w1;
    }
    const float invQ = 1.0f / 196.0f;
    float b = bo[f];
    out[(size_t)(p0 + 0) * E_N + f] = b + acc.x * invQ;
    out[(size_t)(p0 + 1) * E_N + f] = b + acc.y * invQ;
    out[(size_t)(p0 + 2) * E_N + f] = b + acc.z * invQ;
    out[(size_t)(p0 + 3) * E_N + f] = b + acc.w * invQ;
}

// ---------------------------------------------------------------------------
extern "C" void kernel_launch(void* const* d_in, const int* in_sizes, int n_in,
                              void* d_out, int out_size, void* d_ws, size_t ws_size,
                              hipStream_t stream) {
    const float* image = (const float*)d_in[0];
    const float* text  = (const float*)d_in[1];
    const int*   mask  = (const int*)d_in[2];
    const float* Wq    = (const float*)d_in[3];
    const float* Wk    = (const float*)d_in[4];
    const float* Wv    = (const float*)d_in[5];
    const float* Wo    = (const float*)d_in[6];
    const float* bo    = (const float*)d_in[7];
    float* out = (float*)d_out;

    // workspace: qproj | kproj | vproj | pooled | WoT | mode
    float* qproj  = (float*)d_ws;
    float* kproj  = qproj + (size_t)I_N * Q_N * H_N * D_N;
    float* vproj  = kproj + (size_t)T_N * K_N * H_N * D_N;
    float* pooled = vproj + (size_t)T_N * K_N * H_N * D_N;
    float* WoT    = pooled + (size_t)I_N * T_N * E_N;
    int*   mode   = (int*)(WoT + (size_t)E_N * E_N);

    float* attn  = out + (size_t)I_N * T_N * E_N;
    float* tattn = attn + (size_t)I_N * T_N * H_N * Q_N * K_N;

    detect_mask_kernel<<<1, 512, 0, stream>>>((const unsigned int*)mask, mode);
    proj_q_kernel<<<(I_N * Q_N * H_N) / 16, 256, 0, stream>>>(image, Wq, qproj);
    proj_kv_kernel<<<(T_N * K_N * H_N) / 16, 256, 0, stream>>>(text, Wk, Wv, kproj, vproj);
    transpose_wo_kernel<<<dim3(16, 16), 256, 0, stream>>>(Wo, WoT);
    attn_kernel<<<I_N * T_N * H_N, 256, 0, stream>>>(qproj, kproj, vproj, mask, mode,
                                                     attn, tattn, pooled);
    fc_out_kernel<<<dim3((I_N * T_N) / 4, 2), 256, 0, stream>>>(pooled, WoT, bo, out);
}